// Round 2
// baseline (149.647 us; speedup 1.0000x reference)
//
#include <hip/hip_runtime.h>
#include <cstdint>
#include <cstddef>

// SpectralGraphConv: B=8, N=1024, C_IN=C_OUT=64, K=4
//   z0 = x, z1 = L x, z_k = 2 L z_{k-1} - z_{k-2},  out = sum_k z_k @ theta[k]
//
// Round-2 structure: LDS-free K-loop via transposed product.
//   z_nextT[c][m] = sum_k zT[c][k] * L[m][k]
//   A-frag = zT rows (K-contig, bf16, L2-hot), B-frag = row-major L directly
//   (B-frag layout col=lane&15 -> m-row, 8 K-contig elems -> contiguous 32B f32).
//   D-frag is zT-oriented -> written straight back as next stage's A operand.
// Wave tile 16c x 16m -> 2048 waves/stage (8 waves/CU), 8-deep reg pipeline.
// Theta phase: relay z tile through small padded LDS, 2 MFMAs vs thetaT.

typedef __bf16 bf16;
typedef bf16 bf16x8 __attribute__((ext_vector_type(8)));   // MFMA A/B frag
typedef float f32x4 __attribute__((ext_vector_type(4)));   // MFMA C/D frag

#define MFMA_BF16(a, b, c) __builtin_amdgcn_mfma_f32_16x16x32_bf16((a), (b), (c), 0, 0, 0)

// ---------------------------------------------------------------------------
// prep: blocks 0..127: x[b][n0+64][64] -> xT[b][c][n] (bf16) + xb[b][n][c] (bf16)
//       blocks 128..131: theta[k][c][o] -> thT[k][o][c] (bf16)
// ---------------------------------------------------------------------------
__global__ __launch_bounds__(256) void prep_kernel(const float* __restrict__ x,
                                                   const float* __restrict__ theta,
                                                   bf16* __restrict__ xT,
                                                   bf16* __restrict__ xb,
                                                   bf16* __restrict__ thT)
{
    __shared__ bf16 tile[64][72];
    const int bid = blockIdx.x;
    const int t = threadIdx.x;
    const int r = t >> 2;            // 0..63 source row
    const int c0 = (t & 3) << 4;     // 0,16,32,48 source col chunk

    const float* src;
    bf16* dstT;
    int dst_ld;
    const bool isx = bid < 128;
    int b = 0, n0 = 0;
    if (isx) {
        b = bid >> 4; n0 = (bid & 15) << 6;
        src = x + (size_t)(b * 1024 + n0) * 64;
        dstT = xT + (size_t)b * 64 * 1024 + n0;
        dst_ld = 1024;
    } else {
        const int k = bid - 128;
        src = theta + (size_t)k * 4096;
        dstT = thT + (size_t)k * 4096;
        dst_ld = 64;
    }

    bf16x8 row0, row1;
#pragma unroll
    for (int j = 0; j < 16; j += 4) {
        f32x4 v = *reinterpret_cast<const f32x4*>(src + r * 64 + c0 + j);
#pragma unroll
        for (int i = 0; i < 4; ++i) {
            bf16 q = (bf16)v[i];
            tile[r][c0 + j + i] = q;
            if (j + i < 8) row0[j + i] = q; else row1[j + i - 8] = q;
        }
    }
    if (isx) {
        bf16* xr = xb + (size_t)(b * 1024 + n0 + r) * 64 + c0;
        *reinterpret_cast<bf16x8*>(xr) = row0;
        *reinterpret_cast<bf16x8*>(xr + 8) = row1;
    }
    __syncthreads();
    bf16x8 o0, o1;
#pragma unroll
    for (int j = 0; j < 8; ++j) { o0[j] = tile[c0 + j][r]; o1[j] = tile[c0 + 8 + j][r]; }
    *reinterpret_cast<bf16x8*>(dstT + (size_t)r * dst_ld + c0) = o0;
    *reinterpret_cast<bf16x8*>(dstT + (size_t)r * dst_ld + c0 + 8) = o1;
}

// ---------------------------------------------------------------------------
// stage kernel: WG = 4 waves, one 16-row m-tile of one batch.
// wave w owns channels [16w,16w+16): computes zT frag, then out cols [16w,16w+16).
// ---------------------------------------------------------------------------
template <int STAGE>
__global__ __launch_bounds__(256) void stage_kernel(
    const float* __restrict__ Lmat,
    const bf16* __restrict__ xb,       // [b][n][c] bf16 (stage 1 theta phase)
    const bf16* __restrict__ zinT,     // [b][c][n] bf16 (A operand)
    const bf16* __restrict__ zprevT,   // [b][c][n] bf16 (subtract, stages 2,3)
    const bf16* __restrict__ thT,      // [k][o][c] bf16
    bf16* __restrict__ zoutT,          // [b][c][n] bf16 (stages 1,2)
    float* __restrict__ out)           // [b][n][o] f32
{
    __shared__ __align__(16) bf16 zbuf[16][72];   // z tile relay, padded stride

    const int bid = blockIdx.x;
    const int b  = bid >> 6;
    const int m0 = (bid & 63) << 4;
    const int t  = threadIdx.x;
    const int w  = t >> 6;
    const int l  = t & 63;
    const int l15 = l & 15;
    const int lg  = l >> 4;
    const int c0  = w << 4;

    const bf16*  aptr = zinT + (size_t)(b * 64 + c0 + l15) * 1024 + lg * 8;
    const float* bptr = Lmat + (size_t)(b * 1024 + m0 + l15) * 1024 + lg * 8;

    f32x4 acc = {0.f, 0.f, 0.f, 0.f};

    constexpr int DEPTH = 8;               // k-steps in flight (k-step = 32)
    bf16x8 aR[DEPTH];
    f32x4  b0R[DEPTH], b1R[DEPTH];
#pragma unroll
    for (int u = 0; u < DEPTH; ++u) {
        aR[u]  = *reinterpret_cast<const bf16x8*>(aptr + u * 32);
        b0R[u] = *reinterpret_cast<const f32x4*>(bptr + u * 32);
        b1R[u] = *reinterpret_cast<const f32x4*>(bptr + u * 32 + 4);
    }
    for (int k0 = 0; k0 < 1024 - 32 * DEPTH; k0 += 32 * DEPTH) {
#pragma unroll
        for (int u = 0; u < DEPTH; ++u) {
            bf16x8 bb;
#pragma unroll
            for (int j = 0; j < 4; ++j) { bb[j] = (bf16)b0R[u][j]; bb[4 + j] = (bf16)b1R[u][j]; }
            bf16x8 av = aR[u];
            const int kn = k0 + 32 * DEPTH + u * 32;
            aR[u]  = *reinterpret_cast<const bf16x8*>(aptr + kn);
            b0R[u] = *reinterpret_cast<const f32x4*>(bptr + kn);
            b1R[u] = *reinterpret_cast<const f32x4*>(bptr + kn + 4);
            acc = MFMA_BF16(av, bb, acc);
        }
    }
#pragma unroll
    for (int u = 0; u < DEPTH; ++u) {      // drain tail (no prefetch)
        bf16x8 bb;
#pragma unroll
        for (int j = 0; j < 4; ++j) { bb[j] = (bf16)b0R[u][j]; bb[4 + j] = (bf16)b1R[u][j]; }
        acc = MFMA_BF16(aR[u], bb, acc);
    }

    // ---- epilogue: z = alpha*acc - zprev; D frag = (c=c0+lg*4+r, m=m0+l15) ----
    const int cr = c0 + lg * 4;
    const float alpha = (STAGE == 1) ? 1.0f : 2.0f;
    float zv[4];
#pragma unroll
    for (int r = 0; r < 4; ++r) {
        float zp = 0.f;
        if constexpr (STAGE >= 2)
            zp = (float)zprevT[(size_t)(b * 64 + cr + r) * 1024 + m0 + l15];
        zv[r] = alpha * acc[r] - zp;
    }
    if constexpr (STAGE <= 2) {
#pragma unroll
        for (int r = 0; r < 4; ++r)
            zoutT[(size_t)(b * 64 + cr + r) * 1024 + m0 + l15] = (bf16)zv[r];
    }
#pragma unroll
    for (int r = 0; r < 4; ++r)
        zbuf[l15][cr + r] = (bf16)zv[r];
    __syncthreads();

    // ---- theta phase: out(+)= z @ theta[k]  (+ x @ theta[0] on stage 1) ----
    const int o = (w << 4) + l15;          // output channel column
    f32x4 oacc;
    if constexpr (STAGE == 1) {
        oacc = (f32x4){0.f, 0.f, 0.f, 0.f};
#pragma unroll
        for (int ck = 0; ck < 2; ++ck) {   // x @ theta[0]
            bf16x8 ax = *reinterpret_cast<const bf16x8*>(
                xb + (size_t)(b * 1024 + m0 + l15) * 64 + ck * 32 + lg * 8);
            bf16x8 bt = *reinterpret_cast<const bf16x8*>(
                thT + (size_t)o * 64 + ck * 32 + lg * 8);
            oacc = MFMA_BF16(ax, bt, oacc);
        }
    } else {
#pragma unroll
        for (int r = 0; r < 4; ++r)
            oacc[r] = out[(size_t)(b * 1024 + m0 + lg * 4 + r) * 64 + o];
    }
    constexpr int KTH = (STAGE == 1) ? 1 : STAGE;
#pragma unroll
    for (int ck = 0; ck < 2; ++ck) {
        bf16x8 az = *reinterpret_cast<const bf16x8*>(&zbuf[l15][ck * 32 + lg * 8]);
        bf16x8 bt = *reinterpret_cast<const bf16x8*>(
            thT + (size_t)(KTH * 64 + o) * 64 + ck * 32 + lg * 8);
        oacc = MFMA_BF16(az, bt, oacc);
    }
#pragma unroll
    for (int r = 0; r < 4; ++r)
        out[(size_t)(b * 1024 + m0 + lg * 4 + r) * 64 + o] = oacc[r];
}

// ---------------------------------------------------------------------------
extern "C" void kernel_launch(void* const* d_in, const int* in_sizes, int n_in,
                              void* d_out, int out_size, void* d_ws, size_t ws_size,
                              hipStream_t stream)
{
    const float* x  = (const float*)d_in[0];    // [8,1024,64]
    const float* L  = (const float*)d_in[1];    // [8,1024,1024]
    const float* th = (const float*)d_in[2];    // [4,64,64]
    float* out = (float*)d_out;                 // [8,1024,64]

    // ws (bf16): xT | xb | z1T | z2T | thetaT  (~4.1 MB)
    bf16* xT  = (bf16*)d_ws;
    bf16* xb  = xT  + (size_t)8 * 64 * 1024;
    bf16* z1T = xb  + (size_t)8 * 64 * 1024;
    bf16* z1b = nullptr; (void)z1b;
    bf16* z2T = z1T + (size_t)8 * 64 * 1024;
    bf16* thT = z2T + (size_t)8 * 64 * 1024;

    prep_kernel<<<dim3(132), dim3(256), 0, stream>>>(x, th, xT, xb, thT);
    // stage 1: z1 = L x;            out  = x@th0 + z1@th1
    stage_kernel<1><<<dim3(512), dim3(256), 0, stream>>>(L, xb, xT, xT, thT, z1T, out);
    // stage 2: z2 = 2 L z1 - x;     out += z2@th2
    stage_kernel<2><<<dim3(512), dim3(256), 0, stream>>>(L, xb, z1T, xT, thT, z2T, out);
    // stage 3: z3 = 2 L z2 - z1;    out += z3@th3
    stage_kernel<3><<<dim3(512), dim3(256), 0, stream>>>(L, xb, z2T, z1T, thT, nullptr, out);
}

// Round 3
// 112.170 us; speedup vs baseline: 1.3341x; 1.3341x over previous
//
#include <hip/hip_runtime.h>
#include <cstdint>
#include <cstddef>

// SpectralGraphConv: B=8, N=1024, C_IN=C_OUT=64, K=4
//   z0 = x, z1 = L x, z_k = 2 L z_{k-1} - z_{k-2},  out = sum_k z_k @ theta[k]
//
// Round-3: deep DMA pipeline. Both operands staged to LDS via
// global_load_lds (no VGPR cost -> ~48KB outstanding per WG), D=5 buffers,
// counted vmcnt (never 0 in loop), one raw s_barrier per K-step.
// XOR-swizzled LDS (pre-swizzled global source + swizzled ds_read).
// Operand/D-frag orientation identical to the verified round-2 kernel:
//   A-frag = zT[chan][k..k+8], B-frag = L[m][k..k+8] (f32->bf16 on read),
//   D-frag: col=m0+l15, row-chans cr+r. Epilogue + theta phase verbatim.

typedef __bf16 bf16;
typedef bf16 bf16x8 __attribute__((ext_vector_type(8)));
typedef float f32x4 __attribute__((ext_vector_type(4)));

#define MFMA_BF16(a, b, c) __builtin_amdgcn_mfma_f32_16x16x32_bf16((a), (b), (c), 0, 0, 0)
#define WAITV(n) asm volatile("s_waitcnt vmcnt(" #n ")" ::: "memory")

__device__ __forceinline__ void dma16(const void* g, void* l) {
    __builtin_amdgcn_global_load_lds(
        (const __attribute__((address_space(1))) unsigned int*)g,
        (__attribute__((address_space(3))) unsigned int*)l, 16, 0, 0);
}

// ---------------------------------------------------------------------------
// prep: blocks 0..127: x[b][n0+64][64] -> xT[b][c][n] (bf16) + xb[b][n][c] (bf16)
//       blocks 128..131: theta[k][c][o] -> thT[k][o][c] (bf16)
// ---------------------------------------------------------------------------
__global__ __launch_bounds__(256) void prep_kernel(const float* __restrict__ x,
                                                   const float* __restrict__ theta,
                                                   bf16* __restrict__ xT,
                                                   bf16* __restrict__ xb,
                                                   bf16* __restrict__ thT)
{
    __shared__ bf16 tile[64][72];
    const int bid = blockIdx.x;
    const int t = threadIdx.x;
    const int r = t >> 2;
    const int c0 = (t & 3) << 4;

    const float* src;
    bf16* dstT;
    int dst_ld;
    const bool isx = bid < 128;
    int b = 0, n0 = 0;
    if (isx) {
        b = bid >> 4; n0 = (bid & 15) << 6;
        src = x + (size_t)(b * 1024 + n0) * 64;
        dstT = xT + (size_t)b * 64 * 1024 + n0;
        dst_ld = 1024;
    } else {
        const int k = bid - 128;
        src = theta + (size_t)k * 4096;
        dstT = thT + (size_t)k * 4096;
        dst_ld = 64;
    }

    bf16x8 row0, row1;
#pragma unroll
    for (int j = 0; j < 16; j += 4) {
        f32x4 v = *reinterpret_cast<const f32x4*>(src + r * 64 + c0 + j);
#pragma unroll
        for (int i = 0; i < 4; ++i) {
            bf16 q = (bf16)v[i];
            tile[r][c0 + j + i] = q;
            if (j + i < 8) row0[j + i] = q; else row1[j + i - 8] = q;
        }
    }
    if (isx) {
        bf16* xr = xb + (size_t)(b * 1024 + n0 + r) * 64 + c0;
        *reinterpret_cast<bf16x8*>(xr) = row0;
        *reinterpret_cast<bf16x8*>(xr + 8) = row1;
    }
    __syncthreads();
    bf16x8 o0, o1;
#pragma unroll
    for (int j = 0; j < 8; ++j) { o0[j] = tile[c0 + j][r]; o1[j] = tile[c0 + 8 + j][r]; }
    *reinterpret_cast<bf16x8*>(dstT + (size_t)r * dst_ld + c0) = o0;
    *reinterpret_cast<bf16x8*>(dstT + (size_t)r * dst_ld + c0 + 8) = o1;
}

// ---------------------------------------------------------------------------
// stage kernel: WG = 4 waves, one 16-row m-tile of one batch.
// wave w owns channels [16w,16w+16).
// LDS per stage buffer: L tile 16x64 f32 (4KB, 16B-granule XOR swizzle) +
//                       zT tile 64x64 bf16 (8KB, 16B-granule XOR swizzle).
// ---------------------------------------------------------------------------
template <int STAGE>
__global__ __launch_bounds__(256) void stage_kernel(
    const float* __restrict__ Lmat,
    const bf16* __restrict__ xb,       // [b][n][c] bf16 (stage 1 theta phase)
    const bf16* __restrict__ zinT,     // [b][c][n] bf16 (A operand)
    const bf16* __restrict__ zprevT,   // [b][c][n] bf16 (subtract, stages 2,3)
    const bf16* __restrict__ thT,      // [k][o][c] bf16
    bf16* __restrict__ zoutT,          // [b][c][n] bf16 (stages 1,2)
    float* __restrict__ out)           // [b][n][o] f32
{
    constexpr int D = 5, T = 16, KS = 64, LSTG = 12288;
    __shared__ __align__(16) unsigned char smem[D * LSTG + 16 * 72 * 2];

    const int bid = blockIdx.x;
    const int b  = bid >> 6;
    const int m0 = (bid & 63) << 4;
    const int t  = threadIdx.x;
    const int w  = t >> 6;
    const int l  = t & 63;
    const int l15 = l & 15;
    const int lg  = l >> 4;
    const int c0  = w << 4;

    const float* Lrb = Lmat + ((size_t)(b * 1024 + m0)) * 1024;
    const bf16*  zb  = zinT + (size_t)b * 64 * 1024;

    // --- per-thread staging source constants (pre-swizzled: slot ^ (row&7)) ---
    // L: granule g = t (0..255): row = g>>4, slot = g&15
    const int Lrow = t >> 4, Lslot = t & 15;
    const float* Lsrc = Lrb + (size_t)Lrow * 1024 + (Lslot ^ (Lrow & 7)) * 4;
    // Z: inst q: g = w*128 + q*64 + l: chan = g>>3, slot = g&7
    const int Zg0 = (w << 7) + l, Zg1 = Zg0 + 64;
    const int Zch0 = Zg0 >> 3, Zch1 = Zg1 >> 3;
    const bf16* Zsrc0 = zb + (size_t)Zch0 * 1024 + ((Zg0 & 7) ^ (Zch0 & 7)) * 8;
    const bf16* Zsrc1 = zb + (size_t)Zch1 * 1024 + ((Zg1 & 7) ^ (Zch1 & 7)) * 8;

    auto issue = [&](int k0, unsigned char* bufb) {
        dma16(Lsrc + k0, bufb + (w << 10));                    // L: wave w granules [w*64, +64)
        dma16(Zsrc0 + k0, bufb + 4096 + (w << 11));            // Z q=0
        dma16(Zsrc1 + k0, bufb + 4096 + (w << 11) + 1024);     // Z q=1
    };

    f32x4 acc = {0.f, 0.f, 0.f, 0.f};

    auto computeStep = [&](const unsigned char* bufb) {
        const float* Ll = (const float*)bufb;
        const bf16*  Zl = (const bf16*)(bufb + 4096);
        // A-frags from zT LDS: chan row c0+l15, logical k-granule j = ksub*4+lg
        const int chan = c0 + l15;
        const int sA = chan & 7;
        bf16x8 a0 = *(const bf16x8*)(Zl + (((chan << 3) + (lg ^ sA)) << 3));
        bf16x8 a1 = *(const bf16x8*)(Zl + (((chan << 3) + ((4 + lg) ^ sA)) << 3));
        // B-frags from L LDS (f32 -> bf16): row l15, logical granules 2lg,2lg+1 (+8)
        const int sB = l15 & 7;
        const float* Lr = Ll + (l15 << 6);
        f32x4 u0 = *(const f32x4*)(Lr + ((((lg << 1) | 0) ^ sB) << 2));
        f32x4 u1 = *(const f32x4*)(Lr + ((((lg << 1) | 1) ^ sB) << 2));
        f32x4 v0 = *(const f32x4*)(Lr + (((8 + ((lg << 1) | 0)) ^ sB) << 2));
        f32x4 v1 = *(const f32x4*)(Lr + (((8 + ((lg << 1) | 1)) ^ sB) << 2));
        bf16x8 b0, b1;
#pragma unroll
        for (int j = 0; j < 4; ++j) {
            b0[j] = (bf16)u0[j]; b0[4 + j] = (bf16)u1[j];
            b1[j] = (bf16)v0[j]; b1[4 + j] = (bf16)v1[j];
        }
        acc = MFMA_BF16(a0, b0, acc);
        acc = MFMA_BF16(a1, b1, acc);
    };

    // --- prologue: D-1 stages in flight ---
#pragma unroll
    for (int s = 0; s < D - 1; ++s)
        issue(s * KS, smem + s * LSTG);

    // --- main loop: counted vmcnt (3 DMA insts per stage per wave) ---
#pragma unroll
    for (int tt = 0; tt < T; ++tt) {
        const int rem = (T - 1 - tt) < (D - 2) ? (T - 1 - tt) : (D - 2);
        if (rem >= 3)      WAITV(9);
        else if (rem == 2) WAITV(6);
        else if (rem == 1) WAITV(3);
        else               WAITV(0);
        __builtin_amdgcn_sched_barrier(0);
        __builtin_amdgcn_s_barrier();
        __builtin_amdgcn_sched_barrier(0);
        computeStep(smem + (tt % D) * LSTG);
        if (tt + D - 1 < T)
            issue((tt + D - 1) * KS, smem + ((tt + D - 1) % D) * LSTG);
    }

    // ---- epilogue: z = alpha*acc - zprev; D frag = (c=c0+lg*4+r, m=m0+l15) ----
    bf16 (*zbuf)[72] = (bf16(*)[72])(smem + D * LSTG);
    const int cr = c0 + (lg << 2);
    const float alpha = (STAGE == 1) ? 1.0f : 2.0f;
    float zv[4];
#pragma unroll
    for (int r = 0; r < 4; ++r) {
        float zp = 0.f;
        if constexpr (STAGE >= 2)
            zp = (float)zprevT[(size_t)(b * 64 + cr + r) * 1024 + m0 + l15];
        zv[r] = alpha * acc[r] - zp;
    }
    if constexpr (STAGE <= 2) {
#pragma unroll
        for (int r = 0; r < 4; ++r)
            zoutT[(size_t)(b * 64 + cr + r) * 1024 + m0 + l15] = (bf16)zv[r];
    }
#pragma unroll
    for (int r = 0; r < 4; ++r)
        zbuf[l15][cr + r] = (bf16)zv[r];
    __syncthreads();

    // ---- theta phase: out(+)= z @ theta[k]  (+ x @ theta[0] on stage 1) ----
    const int o = (w << 4) + l15;
    f32x4 oacc;
    if constexpr (STAGE == 1) {
        oacc = (f32x4){0.f, 0.f, 0.f, 0.f};
#pragma unroll
        for (int ck = 0; ck < 2; ++ck) {   // x @ theta[0]
            bf16x8 ax = *reinterpret_cast<const bf16x8*>(
                xb + (size_t)(b * 1024 + m0 + l15) * 64 + ck * 32 + lg * 8);
            bf16x8 bt = *reinterpret_cast<const bf16x8*>(
                thT + (size_t)o * 64 + ck * 32 + lg * 8);
            oacc = MFMA_BF16(ax, bt, oacc);
        }
    } else {
#pragma unroll
        for (int r = 0; r < 4; ++r)
            oacc[r] = out[(size_t)(b * 1024 + m0 + lg * 4 + r) * 64 + o];
    }
    constexpr int KTH = (STAGE == 1) ? 1 : STAGE;
#pragma unroll
    for (int ck = 0; ck < 2; ++ck) {
        bf16x8 az = *reinterpret_cast<const bf16x8*>(&zbuf[l15][ck * 32 + lg * 8]);
        bf16x8 bt = *reinterpret_cast<const bf16x8*>(
            thT + (size_t)(KTH * 64 + o) * 64 + ck * 32 + lg * 8);
        oacc = MFMA_BF16(az, bt, oacc);
    }
#pragma unroll
    for (int r = 0; r < 4; ++r)
        out[(size_t)(b * 1024 + m0 + lg * 4 + r) * 64 + o] = oacc[r];
}

// ---------------------------------------------------------------------------
extern "C" void kernel_launch(void* const* d_in, const int* in_sizes, int n_in,
                              void* d_out, int out_size, void* d_ws, size_t ws_size,
                              hipStream_t stream)
{
    const float* x  = (const float*)d_in[0];    // [8,1024,64]
    const float* L  = (const float*)d_in[1];    // [8,1024,1024]
    const float* th = (const float*)d_in[2];    // [4,64,64]
    float* out = (float*)d_out;                 // [8,1024,64]

    // ws (bf16): xT | xb | z1T | z2T | thetaT  (~4.1 MB)
    bf16* xT  = (bf16*)d_ws;
    bf16* xb  = xT  + (size_t)8 * 64 * 1024;
    bf16* z1T = xb  + (size_t)8 * 64 * 1024;
    bf16* z2T = z1T + (size_t)8 * 64 * 1024;
    bf16* thT = z2T + (size_t)8 * 64 * 1024;

    prep_kernel<<<dim3(132), dim3(256), 0, stream>>>(x, th, xT, xb, thT);
    // stage 1: z1 = L x;            out  = x@th0 + z1@th1
    stage_kernel<1><<<dim3(512), dim3(256), 0, stream>>>(L, xb, xT, xT, thT, z1T, out);
    // stage 2: z2 = 2 L z1 - x;     out += z2@th2
    stage_kernel<2><<<dim3(512), dim3(256), 0, stream>>>(L, xb, z1T, xT, thT, z2T, out);
    // stage 3: z3 = 2 L z2 - z1;    out += z3@th3
    stage_kernel<3><<<dim3(512), dim3(256), 0, stream>>>(L, xb, z2T, z1T, thT, nullptr, out);
}